// Round 1
// baseline (1688.384 us; speedup 1.0000x reference)
//
#include <hip/hip_runtime.h>
#include <hip/hip_bf16.h>

// MPS_BP: y[b,c] chain over 784 sites, chi=64, d=2.
// 160 blocks = 10 channels x 16 batch-tiles(64). 256 threads = 4 waves.
// MFMA mapping (transposed): m = bout, n = batch, k = a.
//   A-op frag: lane row = bout = 16*MT + (l&15), k = 32h + 8*(l>>4) + j  (tensor slice, bf16 in LDS)
//   B-op frag: lane col = batch = 16*NT + (l&15), k = same               (t = running y, bf16 in LDS)
//   D: row(bout) = (l>>4)*4 + r (+16*MT), col(batch) = l&15 (+16*NT)

#define LEN 784
#define NCH 10

typedef short bf16x8 __attribute__((ext_vector_type(8)));
typedef float f32x4  __attribute__((ext_vector_type(4)));

#define AF_STRIDE 136   // shorts per a-row: 128 data + 8 pad (keeps 16B alignment)
#define T_STRIDE   72   // shorts per batch-row: 64 data + 8 pad

__device__ __forceinline__ short f2bf(float f) {
    union { __hip_bfloat16 h; short s; } u;
    u.h = __float2bfloat16(f);
    return u.s;
}
__device__ __forceinline__ int pack2(float a, float b) {
    return (int)(unsigned short)f2bf(a) | ((int)(unsigned short)f2bf(b) << 16);
}

__global__ __launch_bounds__(256, 1)
void mps_fwd(const float* __restrict__ x, const float* __restrict__ tens,
             float* __restrict__ out)
{
    __shared__ short AfB[2][64 * AF_STRIDE]; // [buf][a][ (i*64+bout) ^ (8*((a>>3)&3)) ]  bf16
    __shared__ short tb[2][64 * T_STRIDE];   // [buf][batch][a]  bf16
    __shared__ float xs[2][128];             // [buf][batch*2 + i]

    const int tid  = threadIdx.x;
    const int lane = tid & 63;
    const int w    = tid >> 6;     // wave 0..3
    const int wm   = w >> 1;       // bout half
    const int wt   = w & 1;        // batch half
    const int g    = lane >> 4;    // 0..3
    const int l15  = lane & 15;

    const int bx = blockIdx.x;
    const int ch = bx % NCH;
    const int b0 = (bx / NCH) * 64;

    const float* tbase = tens + (size_t)ch * LEN * 8192; // [site][a][i][bout]

    // staging geometry (per thread: 32 consecutive floats of the site tile)
    const int st_a    = tid >> 2;            // a row
    const int st_rem0 = 32 * (tid & 3);      // start within row (i*64+bout space)
    const int st_key  = 8 * ((st_a >> 3) & 3);

    // ---- init t (site 0 state): t[b][a] = (a==0) ? 1 : 0 ----
    for (int idx = tid; idx < 64 * T_STRIDE; idx += 256) {
        int a = idx % T_STRIDE;
        tb[0][idx] = (a == 0) ? f2bf(1.0f) : (short)0;
        tb[1][idx] = 0;
    }

    // ---- prologue: stage site 0 ----
    {
        const float* src = tbase;
        float4 v[8];
        #pragma unroll
        for (int k = 0; k < 8; ++k)
            v[k] = *(const float4*)(src + tid * 32 + k * 4);
        float xv = 0.f;
        if (tid < 128)
            xv = x[(size_t)(b0 + (tid >> 1)) * (2 * LEN) + (size_t)(tid & 1) * LEN + 0];
        int arr[16];
        #pragma unroll
        for (int k = 0; k < 8; ++k) {
            arr[2 * k]     = pack2(v[k].x, v[k].y);
            arr[2 * k + 1] = pack2(v[k].z, v[k].w);
        }
        #pragma unroll
        for (int c = 0; c < 4; ++c)
            *(int4*)&AfB[0][st_a * AF_STRIDE + ((st_rem0 + 8 * c) ^ st_key)] = ((int4*)arr)[c];
        if (tid < 128) xs[0][tid] = xv;
    }
    __syncthreads();

    for (int n = 0; n < LEN; ++n) {
        const int cur = n & 1;
        const int nxt = cur ^ 1;
        const bool have_next = (n + 1 < LEN);

        // ---- issue next-site global loads early (hide HBM/L2 latency under compute) ----
        float4 pre[8];
        float xv = 0.f;
        if (have_next) {
            const float* src = tbase + (size_t)(n + 1) * 8192;
            #pragma unroll
            for (int k = 0; k < 8; ++k)
                pre[k] = *(const float4*)(src + tid * 32 + k * 4);
            if (tid < 128)
                xv = x[(size_t)(b0 + (tid >> 1)) * (2 * LEN) + (size_t)(tid & 1) * LEN + (n + 1)];
        }

        // ---- B-operand frags: t (running state) ----
        bf16x8 tf[2][2]; // [ntl][h]
        #pragma unroll
        for (int ntl = 0; ntl < 2; ++ntl) {
            int bat = 16 * (2 * wt + ntl) + l15;
            #pragma unroll
            for (int h = 0; h < 2; ++h)
                tf[ntl][h] = *(const bf16x8*)&tb[cur][bat * T_STRIDE + 32 * h + 8 * g];
        }

        // ---- A-operand frags (tensor slice) + MFMA ----
        f32x4 acc[2][2][2]; // [i][m][ntl]
        #pragma unroll
        for (int i = 0; i < 2; ++i)
            #pragma unroll
            for (int m = 0; m < 2; ++m)
                #pragma unroll
                for (int ntl = 0; ntl < 2; ++ntl)
                    acc[i][m][ntl] = (f32x4){0.f, 0.f, 0.f, 0.f};

        #pragma unroll
        for (int i = 0; i < 2; ++i) {
            #pragma unroll
            for (int m = 0; m < 2; ++m) {
                int bout = 16 * (2 * wm + m) + l15;
                int off  = (i * 64 + bout) ^ (8 * g);   // matches staging swizzle: key(a)=8*((a>>3)&3)=8g
                #pragma unroll
                for (int h = 0; h < 2; ++h) {
                    bf16x8 af;
                    #pragma unroll
                    for (int j = 0; j < 8; ++j) {
                        int a = 32 * h + 8 * g + j;
                        af[j] = AfB[cur][a * AF_STRIDE + off];
                    }
                    #pragma unroll
                    for (int ntl = 0; ntl < 2; ++ntl)
                        acc[i][m][ntl] = __builtin_amdgcn_mfma_f32_16x16x32_bf16(
                            af, tf[ntl][h], acc[i][m][ntl], 0, 0, 0);
                }
            }
        }

        // ---- combine with x, activation, write next state (or output) ----
        if (n == LEN - 1) {
            // dims[784]==1: only bout==0 matters; no activation on last site
            if (wm == 0 && g == 0) {
                #pragma unroll
                for (int ntl = 0; ntl < 2; ++ntl) {
                    int col = 16 * (2 * wt + ntl) + l15;
                    float x0 = xs[cur][col * 2 + 0];
                    float x1 = xs[cur][col * 2 + 1];
                    float v = x0 * acc[0][0][ntl][0] + x1 * acc[1][0][ntl][0];
                    out[(size_t)(b0 + col) * NCH + ch] = v;
                }
            }
        } else {
            int e1 = (n + 1) < 6 ? (1 << (n + 1)) : 64;
            int e2 = (783 - n) < 6 ? (1 << (783 - n)) : 64;
            int dout = e1 < e2 ? e1 : e2;
            #pragma unroll
            for (int m = 0; m < 2; ++m) {
                int boutbase = 16 * (2 * wm + m) + 4 * g;
                #pragma unroll
                for (int ntl = 0; ntl < 2; ++ntl) {
                    int col = 16 * (2 * wt + ntl) + l15;
                    float x0 = xs[cur][col * 2 + 0];
                    float x1 = xs[cur][col * 2 + 1];
                    #pragma unroll
                    for (int rp = 0; rp < 2; ++rp) {
                        short s[2];
                        #pragma unroll
                        for (int q = 0; q < 2; ++q) {
                            int r = 2 * rp + q;
                            int bout = boutbase + r;
                            float v = x0 * acc[0][m][ntl][r] + x1 * acc[1][m][ntl][r];
                            // (tanh(v)+1)/2 == 1/(1+exp2(-2*log2(e)*v))
                            float ex = exp2f(-2.88539008177792681f * v);
                            float sg = __builtin_amdgcn_rcpf(1.0f + ex);
                            s[q] = (bout < dout) ? f2bf(sg) : (short)0;
                        }
                        int pk = (int)(unsigned short)s[0] | ((int)s[1] << 16);
                        *(int*)&tb[nxt][col * T_STRIDE + boutbase + 2 * rp] = pk;
                    }
                }
            }
        }

        // ---- write staged next-site data to LDS ----
        if (have_next) {
            int arr[16];
            #pragma unroll
            for (int k = 0; k < 8; ++k) {
                arr[2 * k]     = pack2(pre[k].x, pre[k].y);
                arr[2 * k + 1] = pack2(pre[k].z, pre[k].w);
            }
            #pragma unroll
            for (int c = 0; c < 4; ++c)
                *(int4*)&AfB[nxt][st_a * AF_STRIDE + ((st_rem0 + 8 * c) ^ st_key)] = ((int4*)arr)[c];
            if (tid < 128) xs[nxt][tid] = xv;
        }
        __syncthreads();
    }
}

extern "C" void kernel_launch(void* const* d_in, const int* in_sizes, int n_in,
                              void* d_out, int out_size, void* d_ws, size_t ws_size,
                              hipStream_t stream) {
    (void)in_sizes; (void)n_in; (void)d_ws; (void)ws_size; (void)out_size;
    const float* x    = (const float*)d_in[0];
    const float* tens = (const float*)d_in[1];
    float* out = (float*)d_out;
    hipLaunchKernelGGL(mps_fwd, dim3(160), dim3(256), 0, stream, x, tens, out);
}

// Round 2
// 945.080 us; speedup vs baseline: 1.7865x; 1.7865x over previous
//
#include <hip/hip_runtime.h>
#include <hip/hip_bf16.h>

// MPS chain: y[b,c] over 784 sites, chi=64, d=2, 10 channels, batch 1024.
// 160 blocks (10 ch x 16 batch-tiles of 64) x 1024 threads (16 waves, 4/SIMD).
// Pre-pass transposes tensors -> bf16 ws[ch][site][c=i*64+bout][a] with bank
// swizzle baked in (short index a ^ ((c&7)<<3)), so the main loop stages each
// 16KB site tile with ONE global_load_lds_dwordx4 per thread (linear LDS dest)
// and reads A-fragments as conflict-free ds_read_b128.
// MFMA mapping (verified R1): m=bout (A-op, lane row=l15), n=batch (B-op=t),
// k=a; D row(bout)=4g+r, col(batch)=l15.

#define LEN 784
#define NCH 10

typedef short bf16x8 __attribute__((ext_vector_type(8)));
typedef float f32x4  __attribute__((ext_vector_type(4)));

#define WSA_SHORTS ((size_t)NCH * LEN * 8192)   // 128.45 MB as bytes*2
#define WSX_FLOATS ((size_t)LEN * 2048)         // 6.42 MB
#define WS_NEED (WSA_SHORTS * 2 + WSX_FLOATS * 4)

__device__ __forceinline__ unsigned short f2bf(float f) {
    union { __hip_bfloat16 h; unsigned short s; } u;
    u.h = __float2bfloat16(f);
    return u.s;
}

__device__ __forceinline__ void gload_lds16(const void* g, void* l) {
    __builtin_amdgcn_global_load_lds(
        (const __attribute__((address_space(1))) unsigned int*)g,
        (__attribute__((address_space(3))) unsigned int*)l, 16, 0, 0);
}

// ---------------- pre-pass: transpose+convert tensors, transpose x ----------
__global__ __launch_bounds__(1024) void prepass(const float* __restrict__ x,
                                                const float* __restrict__ tens,
                                                short* __restrict__ wsA,
                                                float* __restrict__ wsX)
{
    const int bid = blockIdx.x;
    const int t = threadIdx.x;
    if (bid < NCH * LEN) {
        __shared__ float tile[64][129];
        const float* src = tens + (size_t)bid * 8192;   // [a][c], c = i*64+bout
        float4 u0 = *(const float4*)(src + 8 * t);
        float4 u1 = *(const float4*)(src + 8 * t + 4);
        int a = t >> 4, c0 = (t & 15) * 8;
        tile[a][c0 + 0] = u0.x; tile[a][c0 + 1] = u0.y;
        tile[a][c0 + 2] = u0.z; tile[a][c0 + 3] = u0.w;
        tile[a][c0 + 4] = u1.x; tile[a][c0 + 5] = u1.y;
        tile[a][c0 + 6] = u1.z; tile[a][c0 + 7] = u1.w;
        __syncthreads();
        // out row c (64 shorts): slot s holds M[s ^ ((c&7)*8)][c]
        int c = t >> 3, q = t & 7;
        int a0 = 8 * (q ^ (c & 7));
        unsigned int w[4];
        #pragma unroll
        for (int p = 0; p < 4; ++p) {
            unsigned short s0 = f2bf(tile[a0 + 2 * p][c]);
            unsigned short s1 = f2bf(tile[a0 + 2 * p + 1][c]);
            w[p] = (unsigned)s0 | ((unsigned)s1 << 16);
        }
        *(int4*)(wsA + (size_t)bid * 8192 + c * 64 + 8 * q) = *(int4*)w;
    } else {
        // x[b][i][n] -> wsX[n][b*2+i]
        int n = bid - NCH * LEN;
        #pragma unroll
        for (int k = 0; k < 2; ++k) {
            int c2 = t + k * 1024;
            wsX[(size_t)n * 2048 + c2] =
                x[(size_t)(c2 >> 1) * (2 * LEN) + (size_t)(c2 & 1) * LEN + n];
        }
    }
}

// ---------------- main chain kernel ----------------
template <bool USE_WS>
__global__ __launch_bounds__(1024, 4) void mps_fwd2(const float* __restrict__ x,
                                                    const float* __restrict__ tens,
                                                    const short* __restrict__ wsA,
                                                    const float* __restrict__ wsX,
                                                    float* __restrict__ out)
{
    __shared__ short A[2][8192];        // [buf][c*64 + swizzled a], linear for DMA
    __shared__ short tbuf[2][64 * 72];  // [buf][batch][a], +8 pad shorts/row

    const int tid = threadIdx.x;
    const int lane = tid & 63;
    const int w = tid >> 6;             // wave 0..15
    const int wm = w >> 2, wt = w & 3;  // bout-tile, batch-tile
    const int g = lane >> 4, l15 = lane & 15;
    const int bx = blockIdx.x;
    const int ch = bx % NCH, b0 = (bx / NCH) * 64;

    const short* wsrc = wsA + (size_t)ch * LEN * 8192;
    const float* tsrc = tens + (size_t)ch * LEN * 8192;

    // fallback staging geometry: thread = (c, q-octet)
    const int fc = tid & 127, fq = tid >> 7;

    // init t(site0): t[b][0]=1, rest 0
    for (int idx = tid; idx < 64 * 72; idx += 1024)
        tbuf[0][idx] = (idx % 72 == 0) ? (short)0x3F80 : (short)0;

    // prologue: stage site 0 into A[0]
    if (USE_WS) {
        gload_lds16(wsrc + 8 * tid, &A[0][w * 512]);
    } else {
        float pre[8];
        #pragma unroll
        for (int j = 0; j < 8; ++j) pre[j] = tsrc[(8 * fq + j) * 128 + fc];
        unsigned int pk[4];
        #pragma unroll
        for (int p = 0; p < 4; ++p)
            pk[p] = (unsigned)f2bf(pre[2 * p]) | ((unsigned)f2bf(pre[2 * p + 1]) << 16);
        *(int4*)&A[0][fc * 64 + 8 * (fq ^ (fc & 7))] = *(int4*)pk;
    }
    __syncthreads();

    const int col = 16 * wt + l15;      // batch column within tile

    for (int n = 0; n < LEN; ++n) {
        const int cur = n & 1, nxt = cur ^ 1;

        // ---- issue next-site staging early ----
        float pre[8];
        if (n + 1 < LEN) {
            if (USE_WS) {
                gload_lds16(wsrc + (size_t)(n + 1) * 8192 + 8 * tid, &A[nxt][w * 512]);
            } else {
                const float* s2 = tsrc + (size_t)(n + 1) * 8192;
                #pragma unroll
                for (int j = 0; j < 8; ++j) pre[j] = s2[(8 * fq + j) * 128 + fc];
            }
        }

        // ---- x pair for this site ----
        float x0, x1;
        if (USE_WS) {
            float2 xv = *(const float2*)(wsX + (size_t)n * 2048 + 2 * (b0 + col));
            x0 = xv.x; x1 = xv.y;
        } else {
            x0 = x[(size_t)(b0 + col) * (2 * LEN) + n];
            x1 = x[(size_t)(b0 + col) * (2 * LEN) + LEN + n];
        }

        // ---- B-op frags: t ----
        bf16x8 tf0 = *(const bf16x8*)&tbuf[cur][col * 72 + 8 * g];
        bf16x8 tf1 = *(const bf16x8*)&tbuf[cur][col * 72 + 32 + 8 * g];

        // ---- A-op frags + MFMA ----
        f32x4 acc[2];
        acc[0] = (f32x4){0.f, 0.f, 0.f, 0.f};
        acc[1] = (f32x4){0.f, 0.f, 0.f, 0.f};
        #pragma unroll
        for (int i = 0; i < 2; ++i) {
            const short* base = &A[cur][(i * 64 + 16 * wm + l15) * 64];
            bf16x8 af0 = *(const bf16x8*)&base[8 * ((0 + g) ^ (l15 & 7))];
            bf16x8 af1 = *(const bf16x8*)&base[8 * ((4 + g) ^ (l15 & 7))];
            acc[i] = __builtin_amdgcn_mfma_f32_16x16x32_bf16(af0, tf0, acc[i], 0, 0, 0);
            acc[i] = __builtin_amdgcn_mfma_f32_16x16x32_bf16(af1, tf1, acc[i], 0, 0, 0);
        }

        // ---- combine + activation + state write (or final output) ----
        if (n == LEN - 1) {
            if (wm == 0 && g == 0) {
                float v = x0 * acc[0][0] + x1 * acc[1][0];
                out[(size_t)(b0 + col) * NCH + ch] = v;
            }
        } else {
            int e1 = (n + 1) < 6 ? (1 << (n + 1)) : 64;
            int e2 = (783 - n) < 6 ? (1 << (783 - n)) : 64;
            int dout = e1 < e2 ? e1 : e2;
            int bb = 16 * wm + 4 * g;
            unsigned int pk2[2];
            #pragma unroll
            for (int p = 0; p < 2; ++p) {
                unsigned short sv[2];
                #pragma unroll
                for (int qq = 0; qq < 2; ++qq) {
                    int r = 2 * p + qq;
                    float v = x0 * acc[0][r] + x1 * acc[1][r];
                    // (tanh(v)+1)/2 == 1/(1+exp2(-2*log2e*v))
                    float ex = exp2f(-2.88539008177792681f * v);
                    float sg = __builtin_amdgcn_rcpf(1.0f + ex);
                    sv[qq] = (bb + r < dout) ? f2bf(sg) : (unsigned short)0;
                }
                pk2[p] = (unsigned)sv[0] | ((unsigned)sv[1] << 16);
            }
            *(int2*)&tbuf[nxt][col * 72 + bb] = *(int2*)pk2;
        }

        // ---- fallback: write staged regs to A[nxt] ----
        if (!USE_WS && n + 1 < LEN) {
            unsigned int pk[4];
            #pragma unroll
            for (int p = 0; p < 4; ++p)
                pk[p] = (unsigned)f2bf(pre[2 * p]) | ((unsigned)f2bf(pre[2 * p + 1]) << 16);
            *(int4*)&A[nxt][fc * 64 + 8 * (fq ^ (fc & 7))] = *(int4*)pk;
        }

        __syncthreads();
    }
}

extern "C" void kernel_launch(void* const* d_in, const int* in_sizes, int n_in,
                              void* d_out, int out_size, void* d_ws, size_t ws_size,
                              hipStream_t stream) {
    (void)in_sizes; (void)n_in; (void)out_size;
    const float* x    = (const float*)d_in[0];
    const float* tens = (const float*)d_in[1];
    float* out = (float*)d_out;
    if (ws_size >= WS_NEED) {
        short* wsA = (short*)d_ws;
        float* wsX = (float*)((char*)d_ws + WSA_SHORTS * 2);
        hipLaunchKernelGGL(prepass, dim3(NCH * LEN + LEN), dim3(1024), 0, stream,
                           x, tens, wsA, wsX);
        hipLaunchKernelGGL((mps_fwd2<true>), dim3(160), dim3(1024), 0, stream,
                           x, tens, wsA, wsX, out);
    } else {
        hipLaunchKernelGGL((mps_fwd2<false>), dim3(160), dim3(1024), 0, stream,
                           x, tens, (const short*)nullptr, (const float*)nullptr, out);
    }
}

// Round 3
// 916.696 us; speedup vs baseline: 1.8418x; 1.0310x over previous
//
#include <hip/hip_runtime.h>
#include <hip/hip_bf16.h>

// MPS chain: y[b,c] over 784 sites, chi=64, d=2, 10 ch, batch 1024.
// 160 blocks (ch x 16 batch-tiles of 64) x 256 thr (4 waves, 1/SIMD).
// Wave (mh,nh) = 32x32 output quadrant via 16 x mfma_f32_16x16x32_bf16.
// A-fragments: PRE-LAID in wsA in per-lane frag order -> 8 global_load_dwordx4
// per wave per site, loaded one site ahead into regs (no LDS for A).
// t-state: 8KB in LDS, octet-XOR swizzle (a-octet ^ (col&7)) -> b128 reads
// and int2 writes both at the bank minimum.
// Layouts (verified R1/R2): A row=l&15, k=8*(l>>4)+j; B col=l&15, same k;
// D row=4*(l>>4)+r, col=l&15.

#define LEN 784
#define NCH 10

typedef short bf16x8 __attribute__((ext_vector_type(8)));
typedef float f32x4  __attribute__((ext_vector_type(4)));

#define WSA_SHORTS ((size_t)NCH * LEN * 8192)
#define WSX_FLOATS ((size_t)LEN * 2048)
#define WS_NEED (WSA_SHORTS * 2 + WSX_FLOATS * 4)

static __device__ __forceinline__ unsigned short f2bf(float f) {
    union { __hip_bfloat16 h; unsigned short s; } u;
    u.h = __float2bfloat16(f);
    return u.s;
}

// ---------------- pre-pass: frag-order bf16 tensors + x transpose ----------
__global__ __launch_bounds__(1024) void prepass(const float* __restrict__ x,
                                                const float* __restrict__ tens,
                                                short* __restrict__ wsA,
                                                float* __restrict__ wsX)
{
    const int bid = blockIdx.x;
    const int t = threadIdx.x;
    if (bid < NCH * LEN) {
        // unit t = [mh][mt][ii][kf][lane]; each writes 8 bf16 (one frag slice)
        const int mh = t >> 9, mt = (t >> 8) & 1, ii = (t >> 7) & 1,
                  kf = (t >> 6) & 1, l = t & 63;
        const int bout = 32 * mh + 16 * mt + (l & 15);
        const int a0 = 32 * kf + 8 * (l >> 4);
        const float* src = tens + (size_t)bid * 8192;   // [a][i][bout]
        unsigned int wv[4];
        #pragma unroll
        for (int p = 0; p < 4; ++p) {
            float f0 = src[(size_t)(a0 + 2 * p) * 128 + ii * 64 + bout];
            float f1 = src[(size_t)(a0 + 2 * p + 1) * 128 + ii * 64 + bout];
            wv[p] = (unsigned)f2bf(f0) | ((unsigned)f2bf(f1) << 16);
        }
        *(int4*)(wsA + (size_t)bid * 8192 + (size_t)t * 8) = *(int4*)wv;
    } else {
        // x[b][i][n] -> wsX[n][2b+i]
        int n = bid - NCH * LEN;
        #pragma unroll
        for (int k = 0; k < 2; ++k) {
            int c2 = t + k * 1024;
            wsX[(size_t)n * 2048 + c2] =
                x[(size_t)(c2 >> 1) * (2 * LEN) + (size_t)(c2 & 1) * LEN + n];
        }
    }
}

// ---------------- main chain kernel ----------------
template <bool USE_WS>
__global__ __launch_bounds__(256, 1) void mps_fwd3(const float* __restrict__ x,
                                                   const float* __restrict__ tens,
                                                   const short* __restrict__ wsA,
                                                   const float* __restrict__ wsX,
                                                   float* __restrict__ out)
{
    __shared__ short tbuf[2][4096];   // [buf][col*64 + swz(a)]

    const int tid = threadIdx.x;
    const int lane = tid & 63;
    const int w = tid >> 6;
    const int mh = w >> 1, nh = w & 1;
    const int g = lane >> 4, l15 = lane & 15;

    // XCD-aware block -> (ch, batch-tile): same ch lands on same XCD (ch<8)
    int p = blockIdx.x, ch, tile;
    if (p < 128) { ch = p & 7; tile = p >> 3; }
    else { int q = p - 128; ch = 8 + (q & 1); tile = q >> 1; }
    const int b0 = tile * 64;

    const short* asrc = wsA + (size_t)ch * LEN * 8192 + (size_t)mh * 4096;
    const float* tsrc = tens + (size_t)ch * LEN * 8192;

    // init t(site0): t[col][a] = (a==0)
    for (int idx = tid; idx < 4096; idx += 256) {
        int col = idx >> 6, a = idx & 63;
        tbuf[0][col * 64 + 8 * ((a >> 3) ^ (col & 7)) + (a & 7)] =
            (a == 0) ? (short)0x3F80 : (short)0;
    }

    // per-lane constant LDS offsets
    int rd_off[2][2]; // [nt][kf]
    int wr_off[2][2]; // [mt][nt]
    #pragma unroll
    for (int nt = 0; nt < 2; ++nt) {
        int col = 32 * nh + 16 * nt + l15;
        #pragma unroll
        for (int kf = 0; kf < 2; ++kf)
            rd_off[nt][kf] = col * 64 + 8 * ((4 * kf + g) ^ (col & 7));
        #pragma unroll
        for (int mt = 0; mt < 2; ++mt) {
            int o = 4 * mh + 2 * mt + (g >> 1);
            wr_off[mt][nt] = col * 64 + 8 * (o ^ (col & 7)) + 4 * (g & 1);
        }
    }

    auto load_afrags = [&](int site, bf16x8 (&A)[8]) {
        if (USE_WS) {
            const short* sb = asrc + (size_t)site * 8192;
            #pragma unroll
            for (int f = 0; f < 8; ++f)
                A[f] = *(const bf16x8*)(sb + f * 512 + lane * 8);
        } else {
            const float* sb = tsrc + (size_t)site * 8192;
            #pragma unroll
            for (int f = 0; f < 8; ++f) {
                int mt = f >> 2, ii = (f >> 1) & 1, kf = f & 1;
                int bout = 32 * mh + 16 * mt + l15;
                int a0 = 32 * kf + 8 * g;
                unsigned int wv[4];
                #pragma unroll
                for (int q2 = 0; q2 < 4; ++q2) {
                    float f0 = sb[(size_t)(a0 + 2 * q2) * 128 + ii * 64 + bout];
                    float f1 = sb[(size_t)(a0 + 2 * q2 + 1) * 128 + ii * 64 + bout];
                    wv[q2] = (unsigned)f2bf(f0) | ((unsigned)f2bf(f1) << 16);
                }
                A[f] = *(bf16x8*)wv;
            }
        }
    };

    auto load_x = [&](int site, float2 (&xv)[2]) {
        #pragma unroll
        for (int nt = 0; nt < 2; ++nt) {
            int b = b0 + 32 * nh + 16 * nt + l15;
            if (USE_WS) {
                xv[nt] = *(const float2*)(wsX + (size_t)site * 2048 + 2 * b);
            } else {
                xv[nt].x = x[(size_t)b * (2 * LEN) + site];
                xv[nt].y = x[(size_t)b * (2 * LEN) + LEN + site];
            }
        }
    };

    auto body = [&](int n, bf16x8 (&Acur)[8], bf16x8 (&Anxt)[8],
                    float2 (&xcur)[2], float2 (&xnxt)[2]) {
        const int cur = n & 1, nxt = cur ^ 1;

        // prefetch next site (in flight across whole site body)
        if (n + 1 < LEN) { load_afrags(n + 1, Anxt); load_x(n + 1, xnxt); }

        // t (B-op) frags
        bf16x8 tf[2][2];
        #pragma unroll
        for (int nt = 0; nt < 2; ++nt)
            #pragma unroll
            for (int kf = 0; kf < 2; ++kf)
                tf[nt][kf] = *(const bf16x8*)&tbuf[cur][rd_off[nt][kf]];

        f32x4 acc[2][2][2]; // [ii][mt][nt]
        #pragma unroll
        for (int ii = 0; ii < 2; ++ii)
            #pragma unroll
            for (int mt = 0; mt < 2; ++mt)
                #pragma unroll
                for (int nt = 0; nt < 2; ++nt)
                    acc[ii][mt][nt] = (f32x4){0.f, 0.f, 0.f, 0.f};

        #pragma unroll
        for (int kf = 0; kf < 2; ++kf)
            #pragma unroll
            for (int mt = 0; mt < 2; ++mt)
                #pragma unroll
                for (int ii = 0; ii < 2; ++ii)
                    #pragma unroll
                    for (int nt = 0; nt < 2; ++nt)
                        acc[ii][mt][nt] = __builtin_amdgcn_mfma_f32_16x16x32_bf16(
                            Acur[mt * 4 + ii * 2 + kf], tf[nt][kf], acc[ii][mt][nt], 0, 0, 0);

        if (n == LEN - 1) {
            // dims[784]==1 -> only bout 0, no activation
            if (mh == 0 && g == 0) {
                #pragma unroll
                for (int nt = 0; nt < 2; ++nt) {
                    float v = xcur[nt].x * acc[0][0][nt][0] + xcur[nt].y * acc[1][0][nt][0];
                    out[(size_t)(b0 + 32 * nh + 16 * nt + l15) * NCH + ch] = v;
                }
            }
        } else {
            int e1 = (n + 1) < 6 ? (1 << (n + 1)) : 64;
            int e2 = (783 - n) < 6 ? (1 << (783 - n)) : 64;
            int dout = e1 < e2 ? e1 : e2;
            #pragma unroll
            for (int mt = 0; mt < 2; ++mt) {
                int abase = 32 * mh + 16 * mt + 4 * g;
                #pragma unroll
                for (int nt = 0; nt < 2; ++nt) {
                    // fold -2*log2(e) into x: u = xs0*acc0 + xs1*acc1
                    float xs0 = xcur[nt].x * -2.88539008177792681f;
                    float xs1 = xcur[nt].y * -2.88539008177792681f;
                    unsigned short sv[4];
                    #pragma unroll
                    for (int r = 0; r < 4; ++r) {
                        float u = xs0 * acc[0][mt][nt][r] + xs1 * acc[1][mt][nt][r];
                        float sg = __builtin_amdgcn_rcpf(1.0f + exp2f(u));
                        sv[r] = (abase + r < dout) ? f2bf(sg) : (unsigned short)0;
                    }
                    int2 pk;
                    pk.x = (int)((unsigned)sv[0] | ((unsigned)sv[1] << 16));
                    pk.y = (int)((unsigned)sv[2] | ((unsigned)sv[3] << 16));
                    *(int2*)&tbuf[nxt][wr_off[mt][nt]] = pk;
                }
            }
        }
        __syncthreads();
    };

    bf16x8 A0[8], A1[8];
    float2 xv0[2], xv1[2];
    load_afrags(0, A0);
    load_x(0, xv0);
    __syncthreads();   // init writes visible

    for (int n = 0; n < LEN; n += 2) {
        body(n, A0, A1, xv0, xv1);
        body(n + 1, A1, A0, xv1, xv0);
    }
}

extern "C" void kernel_launch(void* const* d_in, const int* in_sizes, int n_in,
                              void* d_out, int out_size, void* d_ws, size_t ws_size,
                              hipStream_t stream) {
    (void)in_sizes; (void)n_in; (void)out_size;
    const float* x    = (const float*)d_in[0];
    const float* tens = (const float*)d_in[1];
    float* out = (float*)d_out;
    if (ws_size >= WS_NEED) {
        short* wsA = (short*)d_ws;
        float* wsX = (float*)((char*)d_ws + WSA_SHORTS * 2);
        hipLaunchKernelGGL(prepass, dim3(NCH * LEN + LEN), dim3(1024), 0, stream,
                           x, tens, wsA, wsX);
        hipLaunchKernelGGL((mps_fwd3<true>), dim3(160), dim3(256), 0, stream,
                           x, tens, wsA, wsX, out);
    } else {
        hipLaunchKernelGGL((mps_fwd3<false>), dim3(160), dim3(256), 0, stream,
                           x, tens, (const short*)nullptr, (const float*)nullptr, out);
    }
}

// Round 4
// 610.504 us; speedup vs baseline: 2.7656x; 1.5015x over previous
//
#include <hip/hip_runtime.h>
#include <hip/hip_bf16.h>

// MPS chain: y[b,c] over 784 sites, chi=64, d=2, 10 ch, batch 1024.
// R4: fill the machine. 640 blocks = 10 ch x 64 batch-tiles(16), 256 thr
// (4 waves). Wave w owns bout rows [16w,16w+16) x all 16 batch cols:
// 4 x mfma_f32_16x16x32_bf16 per site (acc[ii] += A[ii][kf] * T[kf]).
// A-frags pre-laid in wsA in exact per-lane order -> 4 global_load_dwordx4
// per wave per site, prefetched one site ahead into regs. t-state = 2x2KB
// LDS, octet-XOR swizzle (oct ^ (col&7)) -> reads/writes at 2-way max (free).
// Layouts (verified R1-R3): A-op m=l&15, k=8*(l>>4)+j; B-op col=l&15 same k;
// D row=4*(l>>4)+r, col=l&15.

#define LEN 784
#define NCH 10

typedef short bf16x8 __attribute__((ext_vector_type(8)));
typedef float f32x4  __attribute__((ext_vector_type(4)));

#define WSA_SHORTS ((size_t)NCH * LEN * 8192)
#define WSX_FLOATS ((size_t)LEN * 2048)
#define WS_NEED (WSA_SHORTS * 2 + WSX_FLOATS * 4)

static __device__ __forceinline__ unsigned short f2bf(float f) {
    union { __hip_bfloat16 h; unsigned short s; } u;
    u.h = __float2bfloat16(f);
    return u.s;
}

// ---- pre-pass: tensors -> bf16 frag-order wsA, x -> wsX[site][2b+i] ----
__global__ __launch_bounds__(1024) void prepass(const float* __restrict__ x,
                                                const float* __restrict__ tens,
                                                short* __restrict__ wsA,
                                                float* __restrict__ wsX)
{
    const int bid = blockIdx.x;
    const int t = threadIdx.x;
    if (bid < NCH * LEN) {
        // t = [w:4][ii:2][kf:2][lane:64]; each thread emits one 8-elem frag slice
        const int w = t >> 8, ii = (t >> 7) & 1, kf = (t >> 6) & 1, l = t & 63;
        const int bout = 16 * w + (l & 15);
        const int a0 = 32 * kf + 8 * (l >> 4);
        const float* src = tens + (size_t)bid * 8192;   // [a][i][bout]
        unsigned int wv[4];
        #pragma unroll
        for (int p = 0; p < 4; ++p) {
            float f0 = src[(size_t)(a0 + 2 * p) * 128 + ii * 64 + bout];
            float f1 = src[(size_t)(a0 + 2 * p + 1) * 128 + ii * 64 + bout];
            wv[p] = (unsigned)f2bf(f0) | ((unsigned)f2bf(f1) << 16);
        }
        *(int4*)(wsA + (size_t)bid * 8192 + (size_t)t * 8) = *(int4*)wv;
    } else {
        int n = bid - NCH * LEN;
        #pragma unroll
        for (int k = 0; k < 2; ++k) {
            int c2 = t + k * 1024;
            wsX[(size_t)n * 2048 + c2] =
                x[(size_t)(c2 >> 1) * (2 * LEN) + (size_t)(c2 & 1) * LEN + n];
        }
    }
}

// ---- main chain kernel ----
template <bool USE_WS>
__global__ __launch_bounds__(256, 4) void mps_fwd4(const float* __restrict__ x,
                                                   const float* __restrict__ tens,
                                                   const short* __restrict__ wsA,
                                                   const float* __restrict__ wsX,
                                                   float* __restrict__ out)
{
    __shared__ short tbuf[2][1024];   // [buf][col*64 + swz(a)], 16 cols x 64 a

    const int tid = threadIdx.x;
    const int lane = tid & 63;
    const int w = tid >> 6;           // wave 0..3 = bout quarter
    const int g = lane >> 4, l15 = lane & 15;

    const int bid = blockIdx.x;
    const int ch = bid >> 6;          // 0..9
    const int b0 = (bid & 63) * 16;   // batch tile of 16

    const short* asrc = wsA + (size_t)ch * LEN * 8192 + (size_t)w * 2048;
    const float* tsrc = tens + (size_t)ch * LEN * 8192;

    // init t(site0): t[col][a] = (a==0), swizzled
    for (int idx = tid; idx < 1024; idx += 256) {
        int col = idx >> 6, a = idx & 63;
        tbuf[0][col * 64 + 8 * ((a >> 3) ^ (col & 7)) + (a & 7)] =
            (a == 0) ? (short)0x3F80 : (short)0;
    }

    // per-lane LDS offsets
    int rd_off[2];  // B-frag per kf: col=l15, a-octet 4kf+g
    #pragma unroll
    for (int kf = 0; kf < 2; ++kf)
        rd_off[kf] = l15 * 64 + 8 * ((4 * kf + g) ^ (l15 & 7));
    // D-write: rows a0=16w+4g..+3 at col l15 -> octet 2w+(g>>1), half g&1
    const int wr_off = l15 * 64 + 8 * ((2 * w + (g >> 1)) ^ (l15 & 7)) + 4 * (g & 1);

    auto load_afrags = [&](int site, bf16x8 (&A)[4]) {
        if (USE_WS) {
            const short* sb = asrc + (size_t)site * 8192;
            #pragma unroll
            for (int f = 0; f < 4; ++f)
                A[f] = *(const bf16x8*)(sb + f * 512 + lane * 8);
        } else {
            const float* sb = tsrc + (size_t)site * 8192;
            #pragma unroll
            for (int f = 0; f < 4; ++f) {
                int ii = f >> 1, kf = f & 1;
                int bout = 16 * w + l15;
                int a0 = 32 * kf + 8 * g;
                unsigned int wv[4];
                #pragma unroll
                for (int p = 0; p < 4; ++p) {
                    float f0 = sb[(size_t)(a0 + 2 * p) * 128 + ii * 64 + bout];
                    float f1 = sb[(size_t)(a0 + 2 * p + 1) * 128 + ii * 64 + bout];
                    wv[p] = (unsigned)f2bf(f0) | ((unsigned)f2bf(f1) << 16);
                }
                A[f] = *(bf16x8*)wv;
            }
        }
    };

    auto load_x = [&](int site, float2& xv) {
        if (USE_WS) {
            xv = *(const float2*)(wsX + (size_t)site * 2048 + 2 * (b0 + l15));
        } else {
            xv.x = x[(size_t)(b0 + l15) * (2 * LEN) + site];
            xv.y = x[(size_t)(b0 + l15) * (2 * LEN) + LEN + site];
        }
    };

    auto body = [&](int n, bf16x8 (&Acur)[4], bf16x8 (&Anxt)[4],
                    float2& xcur, float2& xnxt) {
        const int cur = n & 1, nxt = cur ^ 1;

        // prefetch next site into regs (in flight across this whole body)
        if (n + 1 < LEN) { load_afrags(n + 1, Anxt); load_x(n + 1, xnxt); }

        // B-op frags (t state)
        bf16x8 tf0 = *(const bf16x8*)&tbuf[cur][rd_off[0]];
        bf16x8 tf1 = *(const bf16x8*)&tbuf[cur][rd_off[1]];

        f32x4 acc0 = (f32x4){0.f, 0.f, 0.f, 0.f};
        f32x4 acc1 = (f32x4){0.f, 0.f, 0.f, 0.f};
        acc0 = __builtin_amdgcn_mfma_f32_16x16x32_bf16(Acur[0], tf0, acc0, 0, 0, 0);
        acc0 = __builtin_amdgcn_mfma_f32_16x16x32_bf16(Acur[1], tf1, acc0, 0, 0, 0);
        acc1 = __builtin_amdgcn_mfma_f32_16x16x32_bf16(Acur[2], tf0, acc1, 0, 0, 0);
        acc1 = __builtin_amdgcn_mfma_f32_16x16x32_bf16(Acur[3], tf1, acc1, 0, 0, 0);

        if (n == LEN - 1) {
            // dims[784]==1 -> only bout 0 (w==0, g==0, r==0); no activation
            if (w == 0 && g == 0) {
                float v = xcur.x * acc0[0] + xcur.y * acc1[0];
                out[(size_t)(b0 + l15) * NCH + ch] = v;
            }
        } else {
            int e1 = (n + 1) < 6 ? (1 << (n + 1)) : 64;
            int e2 = (783 - n) < 6 ? (1 << (783 - n)) : 64;
            int dout = e1 < e2 ? e1 : e2;
            int abase = 16 * w + 4 * g;
            float xs0 = xcur.x * -2.88539008177792681f;
            float xs1 = xcur.y * -2.88539008177792681f;
            unsigned short sv[4];
            #pragma unroll
            for (int r = 0; r < 4; ++r) {
                float u = xs0 * acc0[r] + xs1 * acc1[r];
                float sg = __builtin_amdgcn_rcpf(1.0f + exp2f(u));
                sv[r] = (abase + r < dout) ? f2bf(sg) : (unsigned short)0;
            }
            int2 pk;
            pk.x = (int)((unsigned)sv[0] | ((unsigned)sv[1] << 16));
            pk.y = (int)((unsigned)sv[2] | ((unsigned)sv[3] << 16));
            *(int2*)&tbuf[nxt][wr_off] = pk;
        }
        __syncthreads();
    };

    bf16x8 A0[4], A1[4];
    float2 xv0, xv1;
    load_afrags(0, A0);
    load_x(0, xv0);
    __syncthreads();   // t-init visible

    for (int n = 0; n < LEN; n += 2) {
        body(n, A0, A1, xv0, xv1);
        body(n + 1, A1, A0, xv1, xv0);
    }
}

extern "C" void kernel_launch(void* const* d_in, const int* in_sizes, int n_in,
                              void* d_out, int out_size, void* d_ws, size_t ws_size,
                              hipStream_t stream) {
    (void)in_sizes; (void)n_in; (void)out_size;
    const float* x    = (const float*)d_in[0];
    const float* tens = (const float*)d_in[1];
    float* out = (float*)d_out;
    if (ws_size >= WS_NEED) {
        short* wsA = (short*)d_ws;
        float* wsX = (float*)((char*)d_ws + WSA_SHORTS * 2);
        hipLaunchKernelGGL(prepass, dim3(NCH * LEN + LEN), dim3(1024), 0, stream,
                           x, tens, wsA, wsX);
        hipLaunchKernelGGL((mps_fwd4<true>), dim3(640), dim3(256), 0, stream,
                           x, tens, wsA, wsX, out);
    } else {
        hipLaunchKernelGGL((mps_fwd4<false>), dim3(640), dim3(256), 0, stream,
                           x, tens, (const short*)nullptr, (const float*)nullptr, out);
    }
}

// Round 5
// 554.180 us; speedup vs baseline: 3.0466x; 1.1016x over previous
//
#include <hip/hip_runtime.h>
#include <hip/hip_bf16.h>

// MPS chain: y[b,c] over 784 sites, chi=64, d=2, 10 ch, batch 1024.
// R5: keep R4's 640x256 decomposition (wave = 16 bout x 16 batch, 4 MFMA/site)
// but (1) raw s_barrier with lgkmcnt-only wait -> global prefetches stay in
// flight across site barriers (no vmcnt(0) drain), (2) distance-2 prefetch in
// 4 static reg slots, x4-unrolled site loop, (3) XCD-aware block mapping so
// each XCD streams <=2 channels (L2-resident site tiles), (4) x pre-scaled by
// -2*log2(e) in [b][2n+i] layout, float4 per 4 sites.
// Layouts (verified R1-R4): A-op m=l&15, k=8*(l>>4)+j; B-op col=l&15 same k;
// D row=4*(l>>4)+r, col=l&15. t-LDS octet-XOR swizzle (oct ^ (col&7)).

#define LEN 784
#define NCH 10

typedef short bf16x8 __attribute__((ext_vector_type(8)));
typedef float f32x4  __attribute__((ext_vector_type(4)));

#define WSA_SHORTS ((size_t)NCH * LEN * 8192)
#define WSX_FLOATS ((size_t)1024 * 2 * LEN)
#define WS_NEED (WSA_SHORTS * 2 + WSX_FLOATS * 4)

#define XSCALE -2.88539008177792681f   // -2*log2(e)
#define XUNDO  -0.34657359027997264f   // -ln(2)/2 = 1/XSCALE

static __device__ __forceinline__ unsigned short f2bf(float f) {
    union { __hip_bfloat16 h; unsigned short s; } u;
    u.h = __float2bfloat16(f);
    return u.s;
}

// ---- pre-pass ----
__global__ __launch_bounds__(1024) void prepass(const float* __restrict__ x,
                                                const float* __restrict__ tens,
                                                short* __restrict__ wsA,
                                                float* __restrict__ wsX)
{
    const int bid = blockIdx.x;
    const int t = threadIdx.x;
    if (bid < NCH * LEN) {
        // t = [w:4][ii:2][kf:2][lane:64] -> one 8-elem frag slice each
        const int w = t >> 8, ii = (t >> 7) & 1, kf = (t >> 6) & 1, l = t & 63;
        const int bout = 16 * w + (l & 15);
        const int a0 = 32 * kf + 8 * (l >> 4);
        const float* src = tens + (size_t)bid * 8192;   // [a][i][bout]
        unsigned int wv[4];
        #pragma unroll
        for (int p = 0; p < 4; ++p) {
            float f0 = src[(size_t)(a0 + 2 * p) * 128 + ii * 64 + bout];
            float f1 = src[(size_t)(a0 + 2 * p + 1) * 128 + ii * 64 + bout];
            wv[p] = (unsigned)f2bf(f0) | ((unsigned)f2bf(f1) << 16);
        }
        *(int4*)(wsA + (size_t)bid * 8192 + (size_t)t * 8) = *(int4*)wv;
    } else {
        // x[b][i][n] -> wsX[b][2n+i], pre-scaled by XSCALE
        int b = bid - NCH * LEN;     // 0..1023
        if (t < LEN) {
            float v0 = x[(size_t)b * (2 * LEN) + t] * XSCALE;
            float v1 = x[(size_t)b * (2 * LEN) + LEN + t] * XSCALE;
            float2 pk; pk.x = v0; pk.y = v1;
            *(float2*)(wsX + (size_t)b * (2 * LEN) + 2 * t) = pk;
        }
    }
}

// ---- main chain kernel ----
template <bool USE_WS>
__global__ __launch_bounds__(256, 3) void mps_fwd5(const float* __restrict__ x,
                                                   const float* __restrict__ tens,
                                                   const short* __restrict__ wsA,
                                                   const float* __restrict__ wsX,
                                                   float* __restrict__ out)
{
    __shared__ short tbuf[2][1024];   // [buf][col*64 + swz(a)]

    const int tid = threadIdx.x;
    const int lane = tid & 63;
    const int w = tid >> 6;           // bout quarter
    const int g = lane >> 4, l15 = lane & 15;

    // XCD-aware: p%8 = XCD -> contiguous gidx chunk per XCD (<=2 channels)
    const int p = blockIdx.x;
    const int gidx = (p & 7) * 80 + (p >> 3);
    const int ch = gidx >> 6;
    const int b0 = (gidx & 63) * 16;

    const short* asrc = wsA + (size_t)ch * LEN * 8192 + (size_t)w * 2048;
    const float* tsrc = tens + (size_t)ch * LEN * 8192;
    const float* xsrc = USE_WS ? (wsX + (size_t)(b0 + l15) * (2 * LEN))
                               : (x + (size_t)(b0 + l15) * (2 * LEN));

    // init t(site0): t[col][a] = (a==0), swizzled
    for (int idx = tid; idx < 1024; idx += 256) {
        int col = idx >> 6, a = idx & 63;
        tbuf[0][col * 64 + 8 * ((a >> 3) ^ (col & 7)) + (a & 7)] =
            (a == 0) ? (short)0x3F80 : (short)0;
    }

    int rd_off0 = l15 * 64 + 8 * ((0 + g) ^ (l15 & 7));
    int rd_off1 = l15 * 64 + 8 * ((4 + g) ^ (l15 & 7));
    const int wr_off = l15 * 64 + 8 * ((2 * w + (g >> 1)) ^ (l15 & 7)) + 4 * (g & 1);

    auto loadA = [&](int site, bf16x8 (&A)[4]) {
        site = site < LEN ? site : LEN - 1;
        if (USE_WS) {
            const short* sb = asrc + (size_t)site * 8192;
            #pragma unroll
            for (int f = 0; f < 4; ++f)
                A[f] = *(const bf16x8*)(sb + f * 512 + lane * 8);
        } else {
            const float* sb = tsrc + (size_t)site * 8192;
            #pragma unroll
            for (int f = 0; f < 4; ++f) {
                int ii = f >> 1, kf = f & 1;
                int bout = 16 * w + l15;
                int a0 = 32 * kf + 8 * g;
                unsigned int wv[4];
                #pragma unroll
                for (int q2 = 0; q2 < 4; ++q2) {
                    float f0 = sb[(size_t)(a0 + 2 * q2) * 128 + ii * 64 + bout];
                    float f1 = sb[(size_t)(a0 + 2 * q2 + 1) * 128 + ii * 64 + bout];
                    wv[q2] = (unsigned)f2bf(f0) | ((unsigned)f2bf(f1) << 16);
                }
                A[f] = *(bf16x8*)wv;
            }
        }
    };

    // load (x0s,x1s) for sites nb..nb+3 into two float4s (pre-scaled)
    auto loadX = [&](int nb, float4& qa, float4& qb) {
        nb = nb <= LEN - 4 ? nb : LEN - 4;
        if (USE_WS) {
            qa = *(const float4*)(xsrc + 2 * nb);
            qb = *(const float4*)(xsrc + 2 * nb + 4);
        } else {
            float4 xi0 = *(const float4*)(xsrc + nb);        // i=0, sites nb..nb+3
            float4 xi1 = *(const float4*)(xsrc + LEN + nb);  // i=1
            qa.x = xi0.x * XSCALE; qa.y = xi1.x * XSCALE;
            qa.z = xi0.y * XSCALE; qa.w = xi1.y * XSCALE;
            qb.x = xi0.z * XSCALE; qb.y = xi1.z * XSCALE;
            qb.z = xi0.w * XSCALE; qb.w = xi1.w * XSCALE;
        }
    };

    auto body = [&](int n, bf16x8 (&Ac)[4], bf16x8 (&Al)[4], float x0s, float x1s) {
        const int cur = n & 1, nxt = cur ^ 1;

        loadA(n + 2, Al);   // distance-2 prefetch, in flight across 2 barriers

        bf16x8 tf0 = *(const bf16x8*)&tbuf[cur][rd_off0];
        bf16x8 tf1 = *(const bf16x8*)&tbuf[cur][rd_off1];

        f32x4 acc0 = (f32x4){0.f, 0.f, 0.f, 0.f};
        f32x4 acc1 = (f32x4){0.f, 0.f, 0.f, 0.f};
        acc0 = __builtin_amdgcn_mfma_f32_16x16x32_bf16(Ac[0], tf0, acc0, 0, 0, 0);
        acc0 = __builtin_amdgcn_mfma_f32_16x16x32_bf16(Ac[1], tf1, acc0, 0, 0, 0);
        acc1 = __builtin_amdgcn_mfma_f32_16x16x32_bf16(Ac[2], tf0, acc1, 0, 0, 0);
        acc1 = __builtin_amdgcn_mfma_f32_16x16x32_bf16(Ac[3], tf1, acc1, 0, 0, 0);

        if (n == LEN - 1) {
            // dims[784]==1 -> only bout 0; undo x pre-scale; no activation
            if (w == 0 && g == 0) {
                float v = (x0s * acc0[0] + x1s * acc1[0]) * XUNDO;
                out[(size_t)(b0 + l15) * NCH + ch] = v;
            }
        } else {
            int e1 = (n + 1) < 6 ? (1 << (n + 1)) : 64;
            int e2 = (783 - n) < 6 ? (1 << (783 - n)) : 64;
            int dout = e1 < e2 ? e1 : e2;
            int abase = 16 * w + 4 * g;
            unsigned short sv[4];
            #pragma unroll
            for (int r = 0; r < 4; ++r) {
                float u = x0s * acc0[r] + x1s * acc1[r];   // already scaled by -2log2e
                float sg = __builtin_amdgcn_rcpf(1.0f + exp2f(u));
                sv[r] = (abase + r < dout) ? f2bf(sg) : (unsigned short)0;
            }
            int2 pk;
            pk.x = (int)((unsigned)sv[0] | ((unsigned)sv[1] << 16));
            pk.y = (int)((unsigned)sv[2] | ((unsigned)sv[3] << 16));
            *(int2*)&tbuf[nxt][wr_off] = pk;
        }

        // LDS-only fence + barrier: vm loads stay in flight (no vmcnt drain)
        asm volatile("s_waitcnt lgkmcnt(0)\n\ts_barrier" ::: "memory");
    };

    __syncthreads();   // t-init visible

    bf16x8 As0[4], As1[4], As2[4], As3[4];
    float4 xa, xb, xna, xnb;
    loadA(0, As0);
    loadA(1, As1);
    loadX(0, xa, xb);

    for (int nb = 0; nb < LEN; nb += 4) {
        loadX(nb + 4, xna, xnb);
        body(nb + 0, As0, As2, xa.x, xa.y);
        body(nb + 1, As1, As3, xa.z, xa.w);
        body(nb + 2, As2, As0, xb.x, xb.y);
        body(nb + 3, As3, As1, xb.z, xb.w);
        xa = xna; xb = xnb;
    }
}

extern "C" void kernel_launch(void* const* d_in, const int* in_sizes, int n_in,
                              void* d_out, int out_size, void* d_ws, size_t ws_size,
                              hipStream_t stream) {
    (void)in_sizes; (void)n_in; (void)out_size;
    const float* x    = (const float*)d_in[0];
    const float* tens = (const float*)d_in[1];
    float* out = (float*)d_out;
    if (ws_size >= WS_NEED) {
        short* wsA = (short*)d_ws;
        float* wsX = (float*)((char*)d_ws + WSA_SHORTS * 2);
        hipLaunchKernelGGL(prepass, dim3(NCH * LEN + 1024), dim3(1024), 0, stream,
                           x, tens, wsA, wsX);
        hipLaunchKernelGGL((mps_fwd5<true>), dim3(640), dim3(256), 0, stream,
                           x, tens, wsA, wsX, out);
    } else {
        hipLaunchKernelGGL((mps_fwd5<false>), dim3(640), dim3(256), 0, stream,
                           x, tens, (const short*)nullptr, (const float*)nullptr, out);
    }
}